// Round 1
// baseline (94.584 us; speedup 1.0000x reference)
//
#include <hip/hip_runtime.h>

// Difference3DCostVolume: out[b,c,d,h,w] = l[b,c,h,w] - r[b,c,h,w-d], pad 1.0 for w<d
// Shapes: l,r [B=2, C=32, H=128, W=240] f32; out [B, C, D=48, H, W] f32.
// Write-BW bound: 377.5 MB out vs 15.7 MB in.

#define MAX_DISP 48
#define HH 128
#define WW 240

__global__ __launch_bounds__(256) void costvol_kernel(
    const float* __restrict__ l,
    const float* __restrict__ r,
    float* __restrict__ out)
{
    __shared__ float r_row[WW];

    const int bch = blockIdx.x;          // 0 .. B*C*H-1; bch = bc*H + h
    const int h   = bch % HH;
    const int bc  = bch / HH;
    const int tid = threadIdx.x;

    const size_t base_in = (size_t)bch * WW;

    float lval = 0.0f;
    if (tid < WW) {
        r_row[tid] = r[base_in + tid];
        lval       = l[base_in + tid];
    }
    __syncthreads();

    if (tid >= WW) return;
    const int w = tid;

    // out index: ((bc*D + d)*H + h)*W + w
    size_t obase = ((size_t)bc * MAX_DISP * HH + (size_t)h) * WW + (size_t)w;
    const size_t dstride = (size_t)HH * WW;

    #pragma unroll
    for (int d = 0; d < MAX_DISP; ++d) {
        int idx = w - d;
        float rv = r_row[idx < 0 ? 0 : idx];
        float v  = (w >= d) ? (lval - rv) : 1.0f;
        out[obase + (size_t)d * dstride] = v;
    }
}

extern "C" void kernel_launch(void* const* d_in, const int* in_sizes, int n_in,
                              void* d_out, int out_size, void* d_ws, size_t ws_size,
                              hipStream_t stream) {
    const float* l = (const float*)d_in[0];
    const float* r = (const float*)d_in[1];
    float* out = (float*)d_out;

    // B*C*H blocks = 2*32*128 = 8192
    const int nblocks = 2 * 32 * HH;
    costvol_kernel<<<nblocks, 256, 0, stream>>>(l, r, out);
}

// Round 3
// 77.483 us; speedup vs baseline: 1.2207x; 1.2207x over previous
//
#include <hip/hip_runtime.h>

// Difference3DCostVolume: out[b,c,d,h,w] = l[b,c,h,w] - r[b,c,h,w-d], pad 1.0 for w<d
// Shapes: l,r [B=2, C=32, H=128, W=240] f32; out [B, C, D=48, H, W] f32.
// Write-BW bound: 377.5 MB out vs 15.7 MB in. Ceiling (fillBuffer measured): ~6.9 TB/s.
//
// R2: same as R1 but with clang ext_vector_type float4 (HIP_vector_type float4
// is not accepted by __builtin_nontemporal_store).

#define MAX_DISP 48
#define HH 128
#define WW 240
#define NV 60            // float4 per row
#define PAD4 12          // 12 float4 = 48 floats of front padding

typedef float f32x4 __attribute__((ext_vector_type(4)));

__global__ __launch_bounds__(256) void costvol_kernel(
    const f32x4* __restrict__ l4,
    const float* __restrict__ r,
    f32x4* __restrict__ out4)
{
    __shared__ float r_pad[48 + WW];   // 288 floats = 72 float4

    const int bch = blockIdx.x;        // bc*H + h
    const int h   = bch % HH;
    const int bc  = bch / HH;
    const int tid = threadIdx.x;
    const int v   = tid & 63;          // float4 index along W (0..59 active)
    const int kg  = tid >> 6;          // 0..3 -> d-group base

    // Stage r row into padded LDS; pad front with 0 (masked by w>=d anyway).
    if (tid < 48)  r_pad[tid] = 0.0f;
    if (tid < WW)  r_pad[48 + tid] = r[(size_t)bch * WW + tid];

    // l as float4, register-resident
    f32x4 lv = {0.f, 0.f, 0.f, 0.f};
    if (v < NV) lv = l4[(size_t)bch * NV + v];
    __syncthreads();

    if (v >= NV) return;

    const f32x4* rp4 = (const f32x4*)r_pad;
    const size_t  dstride4 = (size_t)HH * NV;            // float4 stride per d
    const int     w0 = 4 * v;                            // first w this thread owns

    #pragma unroll
    for (int iter = 0; iter < 3; ++iter) {
        const int k  = kg + 4 * iter;                    // wave-uniform
        const int d0 = 4 * k;

        // aligned, lane-consecutive LDS reads (conflict-free ds_read_b128)
        f32x4 A = rp4[PAD4 + v - k];                     // r[w0-d0 .. w0-d0+3]
        f32x4 B = rp4[PAD4 + v - k - 1];                 // r[w0-d0-4 .. w0-d0-1]

        size_t ob = ((size_t)(bc * MAX_DISP + d0) * HH + h) * NV + v;

        #pragma unroll
        for (int s = 0; s < 4; ++s) {                    // d = d0 + s
            f32x4 o;
            #pragma unroll
            for (int j = 0; j < 4; ++j) {                // w = w0 + j
                const int src = j - s;                   // compile-time
                float rv = (src >= 0) ? A[src] : B[4 + src];
                o[j] = (w0 + j >= d0 + s) ? (lv[j] - rv) : 1.0f;
            }
            __builtin_nontemporal_store(o, &out4[ob + (size_t)s * dstride4]);
        }
    }
}

extern "C" void kernel_launch(void* const* d_in, const int* in_sizes, int n_in,
                              void* d_out, int out_size, void* d_ws, size_t ws_size,
                              hipStream_t stream) {
    const f32x4* l4 = (const f32x4*)d_in[0];
    const float* r  = (const float*)d_in[1];
    f32x4* out4 = (f32x4*)d_out;

    const int nblocks = 2 * 32 * HH;   // B*C*H = 8192
    costvol_kernel<<<nblocks, 256, 0, stream>>>(l4, r, out4);
}